// Round 17
// baseline (103.807 us; speedup 1.0000x reference)
//
#include <hip/hip_runtime.h>
#include <math.h>

typedef __attribute__((ext_vector_type(8))) short bf16x8;
typedef __attribute__((ext_vector_type(4))) short bf16x4;
typedef __attribute__((ext_vector_type(4))) float f32x4;
typedef __attribute__((ext_vector_type(2))) unsigned int u32x2;

static constexpr int D_MODEL = 1024;
static constexpr int SEQ = 2048;
static constexpr int BATCH = 2;
static constexpr int M_TOT = BATCH * SEQ;   // 4096

__device__ __forceinline__ unsigned short f2bf(float f) {
  unsigned int u = __builtin_bit_cast(unsigned int, f);
  u += 0x7fffu + ((u >> 16) & 1u);   // round-to-nearest-even
  return (unsigned short)(u >> 16);
}

// pack 2 fp32 -> 2 bf16 in one instr (no builtin on gfx950; RNE)
__device__ __forceinline__ unsigned int cvtpk(float lo, float hi) {
  unsigned int r;
  asm volatile("v_cvt_pk_bf16_f32 %0, %1, %2" : "=v"(r) : "v"(lo), "v"(hi));
  return r;
}

// async global -> LDS, 16B per lane.  LDS dst = wave-uniform base + lane*16.
// GLOBAL src is PER-LANE — caller must include the lane offset.
__device__ __forceinline__ void gld16(const unsigned short* g, unsigned short* l) {
  __builtin_amdgcn_global_load_lds(
      (const __attribute__((address_space(1))) unsigned int*)g,
      (__attribute__((address_space(3))) unsigned int*)l, 16, 0, 0);
}

// ---------------- prep (single dispatch): X cvt | weights cvt | rope table ----------------
__global__ void prep_all(const float* __restrict__ x,
                         const float* __restrict__ qw, const float* __restrict__ kw,
                         const float* __restrict__ vw, const float* __restrict__ ow,
                         unsigned short* __restrict__ Xb,
                         unsigned short* __restrict__ Wqb,
                         float2* __restrict__ ct2) {
  constexpr int NX = M_TOT * D_MODEL / 4;     // 2^20 float4 groups
  constexpr int NW = D_MODEL * D_MODEL;       // 2^20 float4 groups (4 weights)
  const int i = blockIdx.x * blockDim.x + threadIdx.x;
  if (i < NX) {
    const float4 v = reinterpret_cast<const float4*>(x)[i];
    ushort4 o;
    o.x = f2bf(v.x); o.y = f2bf(v.y); o.z = f2bf(v.z); o.w = f2bf(v.w);
    reinterpret_cast<ushort4*>(Xb)[i] = o;
  } else if (i < NX + NW) {
    const int k = i - NX;
    const int which = k >> 18;
    const int off = k & 262143;
    const float* src = (which == 0) ? qw : (which == 1) ? kw : (which == 2) ? vw : ow;
    const float4 v = reinterpret_cast<const float4*>(src)[off];
    ushort4 o;
    o.x = f2bf(v.x); o.y = f2bf(v.y); o.z = f2bf(v.z); o.w = f2bf(v.w);
    reinterpret_cast<ushort4*>(Wqb)[k] = o;
  } else {
    const int k = i - NX - NW;                // < SEQ*32
    const int s = k >> 5;
    const int p = k & 31;
    const float inv_freq = powf(10000.0f, -(float)p / 32.0f);
    const float ang = (float)s * inv_freq;
    const int psw = p ^ (((s >> 2) & 1) << 3);
    float2 cs; cs.x = cosf(ang); cs.y = sinf(ang);
    ct2[s * 32 + psw] = cs;
  }
}

// ---------------- GEMM v5 (round-16 proven): BK=64, counted-vmcnt, fast epilogue ----------------
template <int BM, int BN, int MODE>
__global__ __launch_bounds__(256, 2)
void gemm2(const unsigned short* __restrict__ A,
           const unsigned short* __restrict__ W,
           unsigned short* __restrict__ Qd,
           unsigned short* __restrict__ Kd,
           unsigned short* __restrict__ Vd,
           float* __restrict__ Fd,
           const float2* __restrict__ ct2) {
  constexpr int MI = BM / 32, NI = BN / 32;
  constexpr int NKT = D_MODEL / 64;            // 16 k-steps (BK=64)
  constexpr int LOADS = BM / 32 + BN / 32;     // gld16 per wave per stage
  __shared__ __align__(16) unsigned short smem[2 * (BM + BN) * 64];
  unsigned short* Asm = smem;                  // [2][BM*64]
  unsigned short* Bsm = smem + 2 * BM * 64;    // [2][BN*64]
  const int tid  = threadIdx.x;
  const int lane = tid & 63;
  const int wave = tid >> 6;
  const int wm = wave >> 1, wn = wave & 1;
  const int m0 = blockIdx.y * BM;
  const int n0 = blockIdx.x * BN;
  const int lr = lane & 15, lg = lane >> 4;

  auto stage = [&](int buf, int kt) {
    const int k0 = kt * 64;
#pragma unroll
    for (int c = 0; c < BM / 32; ++c) {
      const int ch = c * 4 + wave;
      const int row = ch * 8 + (lane >> 3);
      gld16(&A[(size_t)(m0 + row) * D_MODEL + k0 + ((lane & 7) ^ (row & 7)) * 8],
            &Asm[buf * BM * 64 + ch * 512]);
    }
#pragma unroll
    for (int c = 0; c < BN / 32; ++c) {
      const int ch = c * 4 + wave;
      const int row = ch * 8 + (lane >> 3);
      gld16(&W[(size_t)(n0 + row) * D_MODEL + k0 + ((lane & 7) ^ (row & 7)) * 8],
            &Bsm[buf * BN * 64 + ch * 512]);
    }
  };

  f32x4 acc[MI][NI] = {};

  stage(0, 0);
  stage(1, 1);
  __builtin_amdgcn_sched_barrier(0);

  for (int kt = 0; kt < NKT; ++kt) {
    const int cur = kt & 1;
    if (kt + 1 < NKT) {
      if constexpr (LOADS == 8) asm volatile("s_waitcnt vmcnt(8)" ::: "memory");
      else                      asm volatile("s_waitcnt vmcnt(6)" ::: "memory");
    } else {
      asm volatile("s_waitcnt vmcnt(0)" ::: "memory");
    }
    __builtin_amdgcn_s_barrier();
    __builtin_amdgcn_sched_barrier(0);

    bf16x8 af[MI][2], bfr[NI][2];
#pragma unroll
    for (int i = 0; i < MI; ++i)
#pragma unroll
      for (int ks = 0; ks < 2; ++ks) {
        const int R = wm * (BM / 2) + i * 16 + lr;
        const int p = (ks * 4 + lg) ^ (R & 7);
        af[i][ks] = *reinterpret_cast<const bf16x8*>(&Asm[cur * BM * 64 + R * 64 + p * 8]);
      }
#pragma unroll
    for (int j = 0; j < NI; ++j)
#pragma unroll
      for (int ks = 0; ks < 2; ++ks) {
        const int R = wn * (BN / 2) + j * 16 + lr;
        const int p = (ks * 4 + lg) ^ (R & 7);
        bfr[j][ks] = *reinterpret_cast<const bf16x8*>(&Bsm[cur * BN * 64 + R * 64 + p * 8]);
      }
    asm volatile("s_waitcnt lgkmcnt(0)" ::: "memory");
    __builtin_amdgcn_sched_barrier(0);
    __builtin_amdgcn_s_barrier();            // all waves done reading buf cur
    __builtin_amdgcn_sched_barrier(0);

    if (kt + 2 < NKT) stage(cur, kt + 2);
    __builtin_amdgcn_sched_barrier(0);

#pragma unroll
    for (int ks = 0; ks < 2; ++ks)
#pragma unroll
      for (int i = 0; i < MI; ++i)
#pragma unroll
        for (int j = 0; j < NI; ++j)
          acc[i][j] = __builtin_amdgcn_mfma_f32_16x16x32_bf16(af[i][ks], bfr[j][ks], acc[i][j], 0, 0, 0);
  }
  // loop's final read-complete s_barrier has synced all waves; smem is dead.

  if constexpr (MODE == 2) {
#pragma unroll
    for (int i = 0; i < MI; ++i)
#pragma unroll
      for (int j = 0; j < NI; ++j)
#pragma unroll
        for (int r = 0; r < 4; ++r) {
          const int gm = m0 + wm * (BM / 2) + i * 16 + lg * 4 + r;
          const int gc = n0 + wn * (BN / 2) + j * 16 + lr;
          Fd[(size_t)gm * D_MODEL + gc] = acc[i][j][r];
        }
  } else {
    const int t = n0 >> 10;                    // uniform per block
    const int b = m0 >> 11;
    const int s_base = m0 & 2047;
    if (t < 2) {
      // ---- Q/K: RoPE via LDS table ----
      unsigned short* dstQ = (t == 0) ? Qd : Kd;
      const unsigned short* gsrc = (const unsigned short*)(ct2 + (size_t)s_base * 32);
#pragma unroll
      for (int it = 0; it < 8; ++it) {
        const int ch = wave * 8 + it;
        gld16(&gsrc[ch * 512 + lane * 8], &smem[ch * 512]);
      }
      asm volatile("s_waitcnt vmcnt(0)" ::: "memory");
      __builtin_amdgcn_sched_barrier(0);
      __builtin_amdgcn_s_barrier();
      const float2* tbl = (const float2*)smem;
      const int nbase = (n0 & 1023) >> 6;
#pragma unroll
      for (int i = 0; i < MI; ++i) {
#pragma unroll
        for (int j = 0; j < NI; ++j) {
#pragma unroll
          for (int r = 0; r < 4; ++r) {
            const int sl = wm * (BM / 2) + i * 16 + lg * 4 + r;   // s_local 0..127
            const int h  = j * 16 + lr;                            // 0..63
            const int psw = (h >> 1) ^ (((sl >> 2) & 1) << 3);
            const float2 cs = tbl[sl * 32 + psw];
            float x = acc[i][j][r];
            const float part = __shfl_xor(x, 1, 64);
            x = (h & 1) ? (part * cs.y + x * cs.x) : (x * cs.x - part * cs.y);
            const int n = nbase + wn;
            dstQ[(size_t)((b * 16 + n) * SEQ + s_base + sl) * 64 + h] = f2bf(x);
          }
        }
      }
    } else {
      // ---- V: transpose via LDS, coalesced [bn][h][s] stores ----
      unsigned short* tile = smem;             // [64 cols][136]
      const int row = tid >> 2;                // 0..63
      const int ck  = tid & 3;
      for (int pass = 0; pass < 2; ++pass) {
        __builtin_amdgcn_s_barrier();
        if (wn == pass) {
#pragma unroll
          for (int i = 0; i < MI; ++i)
#pragma unroll
            for (int j = 0; j < NI; ++j)
#pragma unroll
              for (int r = 0; r < 4; ++r)
                tile[(j * 16 + lr) * 136 + wm * 64 + i * 16 + lg * 4 + r] = f2bf(acc[i][j][r]);
        }
        asm volatile("s_waitcnt lgkmcnt(0)" ::: "memory");
        __builtin_amdgcn_sched_barrier(0);
        __builtin_amdgcn_s_barrier();
        const int c = (n0 & 1023) + pass * 64 + row;
        const int n = c >> 6, h = c & 63;
        unsigned short* vrow = &Vd[(size_t)((b * 16 + n) * 64 + h) * SEQ + s_base + ck * 32];
        const unsigned short* lrow = &tile[row * 136 + ck * 32];
#pragma unroll
        for (int k = 0; k < 4; ++k)
          *reinterpret_cast<bf16x8*>(&vrow[k * 8]) = *reinterpret_cast<const bf16x8*>(&lrow[k * 8]);
      }
    }
  }
}

// ---------------- flash attention v14: 2-wave blocks, 4-deep sum-balanced residency ----------------
// q-block = 64 rows (wave owns 32; per-wave core identical to round 14: swapped QK^T,
// cvt_pk P in registers, counted vmcnt, raw barriers, block-shared swizzled K/V).
// Grid (32 bn, 32 y) = 1024 blocks = exactly 4 co-resident per CU.  CU c holds
// y in {a,a+8,a+16,a+24}; j(y) = {31-a, 16+a, 15-a, a} -> per-CU tile sum = 66
// for every a, and the 32-tile chain is co-scheduled with partners summing 34.
__global__ __launch_bounds__(128, 2)
void attn_kernel(const unsigned short* __restrict__ Q,
                 const unsigned short* __restrict__ K,
                 const unsigned short* __restrict__ Vt,
                 unsigned short* __restrict__ AO) {
  __shared__ __align__(16) unsigned short Ksh[2][4096];  // [buf][64 x 64] swizzled
  __shared__ __align__(16) unsigned short Vsh[2][4096];
  const int bn   = blockIdx.x;
  const int y    = blockIdx.y;
  const int a    = y & 7, bsel = y >> 3;
  const int j    = (bsel == 0) ? (31 - a) : (bsel == 1) ? (16 + a)
                 : (bsel == 2) ? (15 - a) : a;            // per-CU quad sums to 66 tiles
  const int wave = threadIdx.x >> 6;                      // 0..1
  const int lane = threadIdx.x & 63;
  const int lr = lane & 15, lg = lane >> 4;
  const int q0 = j * 64 + wave * 32;
  const unsigned short* Qh = Q  + (size_t)bn * SEQ * 64;
  const unsigned short* Kh = K  + (size_t)bn * SEQ * 64;
  const unsigned short* Vh = Vt + (size_t)bn * 64 * SEQ;
  const int b = bn >> 4, n = bn & 15;

  const int srow8 = lane >> 3;
  const int scolb = ((lane & 7) ^ srow8) * 8;

  auto stage = [&](int buf, int k0) {
#pragma unroll
    for (int c = 0; c < 4; ++c) {              // 8 chunks of 8 rows over 2 waves
      const int ch = wave * 4 + c;
      const int row = ch * 8 + srow8;
      gld16(&Kh[(size_t)(k0 + row) * 64 + scolb], &Ksh[buf][ch * 512]);
      gld16(&Vh[(size_t)row * SEQ + k0 + scolb], &Vsh[buf][ch * 512]);
    }
  };

  constexpr float KL2E = 0.125f * 1.44269504088896f;
  const int nt = j + 1;                        // causal k-tiles of 64 for 64-row q-block

  bf16x8 qf[2][2];
#pragma unroll
  for (int mi = 0; mi < 2; ++mi)
#pragma unroll
    for (int ks = 0; ks < 2; ++ks)
      qf[mi][ks] = *reinterpret_cast<const bf16x8*>(
          &Qh[(size_t)(q0 + mi * 16 + lr) * 64 + ks * 32 + lg * 8]);
  asm volatile("s_waitcnt vmcnt(0)" ::: "memory");  // clean slate for counted waits
  __builtin_amdgcn_sched_barrier(0);

  f32x4 o[2][4] = {};
  float ls[2] = {0.f, 0.f};                    // row-sum for q = mi*16+lr (in-lane k)

  stage(0, 0);
  stage(1, 64);
  __builtin_amdgcn_sched_barrier(0);

  for (int t = 0; t < nt; ++t) {
    const int cur = t & 1;
    const int k0 = t * 64;
    if (t + 1 < nt) { asm volatile("s_waitcnt vmcnt(8)" ::: "memory"); }
    else            { asm volatile("s_waitcnt vmcnt(0)" ::: "memory"); }
    __builtin_amdgcn_s_barrier();            // both waves' stage(t) visible
    __builtin_amdgcn_sched_barrier(0);

    const unsigned short* Kc = &Ksh[cur][0];
    const unsigned short* Vc = &Vsh[cur][0];

    // ---- K frags (XOR-swizzled read) + swapped QK^T ----
    bf16x8 kf[4][2];
#pragma unroll
    for (int nj = 0; nj < 4; ++nj)
#pragma unroll
      for (int ks = 0; ks < 2; ++ks) {
        const int R = nj * 16 + lr;
        const int p = (ks * 4 + lg) ^ (R & 7);
        kf[nj][ks] = *reinterpret_cast<const bf16x8*>(&Kc[R * 64 + p * 8]);
      }
    f32x4 sf[2][4] = {};   // sf[mi][nj][r] = S[q=q0+mi*16+lr][k=k0+nj*16+lg*4+r]
    __builtin_amdgcn_s_setprio(1);
#pragma unroll
    for (int nj = 0; nj < 4; ++nj)
#pragma unroll
      for (int ks = 0; ks < 2; ++ks)
#pragma unroll
        for (int mi = 0; mi < 2; ++mi)
          sf[mi][nj] = __builtin_amdgcn_mfma_f32_16x16x32_bf16(kf[nj][ks], qf[mi][ks], sf[mi][nj], 0, 0, 0);
    __builtin_amdgcn_s_setprio(0);

    // ---- V B-frags (b64: 4 consecutive s at row h) — latency hides under exp ----
    bf16x4 vB[4][4];   // [nj][hf]: V[k0+nj*16+lg*4+{0..3}][hf*16+lr]
#pragma unroll
    for (int nj = 0; nj < 4; ++nj)
#pragma unroll
      for (int hf = 0; hf < 4; ++hf) {
        const int R = hf * 16 + lr;
        const int c = nj * 2 + (lg >> 1);
        const int p = ((c ^ (R & 7)) << 3) + (lg & 1) * 4;
        vB[nj][hf] = *reinterpret_cast<const bf16x4*>(&Vc[R * 64 + p]);
      }

    // ---- exp + pack(bf16x2) into registers (no LDS) ----
    u32x2 w[2][4];     // w[mi][nj] = P[q=lr][k=nj*16+lg*4+{0..3}] packed bf16
    if (k0 + 63 <= q0) {                       // fully unmasked (wave-uniform)
#pragma unroll
      for (int mi = 0; mi < 2; ++mi)
#pragma unroll
        for (int nj = 0; nj < 4; ++nj) {
          const float p0 = __builtin_amdgcn_exp2f(sf[mi][nj][0] * KL2E);
          const float p1 = __builtin_amdgcn_exp2f(sf[mi][nj][1] * KL2E);
          const float p2 = __builtin_amdgcn_exp2f(sf[mi][nj][2] * KL2E);
          const float p3 = __builtin_amdgcn_exp2f(sf[mi][nj][3] * KL2E);
          ls[mi] += (p0 + p1) + (p2 + p3);
          w[mi][nj][0] = cvtpk(p0, p1);
          w[mi][nj][1] = cvtpk(p2, p3);
        }
    } else {
#pragma unroll
      for (int mi = 0; mi < 2; ++mi) {
        const int qrow = q0 + mi * 16 + lr;
#pragma unroll
        for (int nj = 0; nj < 4; ++nj) {
          const int kb = k0 + nj * 16 + lg * 4;
          float p[4];
#pragma unroll
          for (int r = 0; r < 4; ++r)
            p[r] = (kb + r <= qrow) ? __builtin_amdgcn_exp2f(sf[mi][nj][r] * KL2E) : 0.0f;
          ls[mi] += (p[0] + p[1]) + (p[2] + p[3]);
          w[mi][nj][0] = cvtpk(p[0], p[1]);
          w[mi][nj][1] = cvtpk(p[2], p[3]);
        }
      }
    }

    asm volatile("s_waitcnt lgkmcnt(0)" ::: "memory");   // kf + vB reads done
    __builtin_amdgcn_sched_barrier(0);
    __builtin_amdgcn_s_barrier();            // both waves done reading buf cur
    __builtin_amdgcn_sched_barrier(0);

    if (t + 2 < nt) stage(cur, (t + 2) * 64);
    __builtin_amdgcn_sched_barrier(0);

    // ---- PV: pure-register 16x16x16 MFMA (A = packed P, B = vB) ----
    __builtin_amdgcn_s_setprio(1);
#pragma unroll
    for (int nj = 0; nj < 4; ++nj)
#pragma unroll
      for (int hf = 0; hf < 4; ++hf)
#pragma unroll
        for (int mi = 0; mi < 2; ++mi)
          o[mi][hf] = __builtin_amdgcn_mfma_f32_16x16x16bf16_1k(
              __builtin_bit_cast(bf16x4, w[mi][nj]), vB[nj][hf], o[mi][hf], 0, 0, 0);
    __builtin_amdgcn_s_setprio(0);
  }

  // ---- final reduce: lanes sharing lr hold partial sums for q=mi*16+lr ----
#pragma unroll
  for (int mi = 0; mi < 2; ++mi) {
    float s = ls[mi];
    s += __shfl_xor(s, 16, 64);
    s += __shfl_xor(s, 32, 64);
    ls[mi] = s;
  }
#pragma unroll
  for (int mi = 0; mi < 2; ++mi)
#pragma unroll
    for (int r = 0; r < 4; ++r) {
      const float sv = __shfl(ls[mi], lg * 4 + r, 64);   // lane lg*4+r holds q=mi*16+lg*4+r
      const float inv = 1.0f / sv;
      const int srow = q0 + mi * 16 + lg * 4 + r;
#pragma unroll
      for (int hf = 0; hf < 4; ++hf) {
        const int h = hf * 16 + lr;
        AO[(size_t)(b * SEQ + srow) * D_MODEL + n * 64 + h] = f2bf(o[mi][hf][r] * inv);
      }
    }
}

// ---------------- launch ----------------
extern "C" void kernel_launch(void* const* d_in, const int* in_sizes, int n_in,
                              void* d_out, int out_size, void* d_ws, size_t ws_size,
                              hipStream_t stream) {
  const float* qw = (const float*)d_in[0];
  const float* kw = (const float*)d_in[1];
  const float* vw = (const float*)d_in[2];
  const float* ow = (const float*)d_in[3];
  const float* x  = (const float*)d_in[4];

  char* ws = (char*)d_ws;
  const size_t XB = (size_t)M_TOT * D_MODEL * 2;      // 8 MB
  const size_t WB = (size_t)D_MODEL * D_MODEL * 2;    // 2 MB
  unsigned short* Xb  = (unsigned short*)ws;  ws += XB;
  unsigned short* Wqb = (unsigned short*)ws;  ws += WB;  // Wq|Wk|Wv|Wo contiguous
  unsigned short* Wkb = (unsigned short*)ws;  ws += WB;
  unsigned short* Wvb = (unsigned short*)ws;  ws += WB;
  unsigned short* Wob = (unsigned short*)ws;  ws += WB;
  unsigned short* Qr  = (unsigned short*)ws;  ws += XB;
  unsigned short* Kr  = (unsigned short*)ws;  ws += XB;
  unsigned short* Vt  = (unsigned short*)ws;  ws += XB;
  unsigned short* AO  = (unsigned short*)ws;  ws += XB;
  float2* ct2 = (float2*)ws;  ws += (size_t)SEQ * 32 * 8;   // interleaved rope table
  (void)Wkb; (void)Wvb;

  // fused prep: X cvt (2^20) + weights cvt (2^20) + rope (65536) in one dispatch
  constexpr int PREP_ITEMS = M_TOT * D_MODEL / 4 + D_MODEL * D_MODEL + SEQ * 32;
  prep_all<<<(PREP_ITEMS + 255) / 256, 256, 0, stream>>>(x, qw, kw, vw, ow, Xb, Wqb, ct2);

  // merged QKV projection: N = 3072
  gemm2<128, 128, 0><<<dim3(3072 / 128, M_TOT / 128), 256, 0, stream>>>(
      Xb, Wqb, Qr, Kr, Vt, nullptr, ct2);

  attn_kernel<<<dim3(BATCH * 16, 32), 128, 0, stream>>>(Qr, Kr, Vt, AO);

  // final projection: N = 1024, 128x64 tile -> 512 blocks
  gemm2<128, 64, 2><<<dim3(D_MODEL / 64, M_TOT / 128), 256, 0, stream>>>(
      AO, Wob, nullptr, nullptr, nullptr, (float*)d_out, nullptr);
}

// Round 18
// 102.811 us; speedup vs baseline: 1.0097x; 1.0097x over previous
//
#include <hip/hip_runtime.h>
#include <math.h>

typedef __attribute__((ext_vector_type(8))) short bf16x8;
typedef __attribute__((ext_vector_type(4))) short bf16x4;
typedef __attribute__((ext_vector_type(4))) float f32x4;
typedef __attribute__((ext_vector_type(2))) unsigned int u32x2;

static constexpr int D_MODEL = 1024;
static constexpr int SEQ = 2048;
static constexpr int BATCH = 2;
static constexpr int M_TOT = BATCH * SEQ;   // 4096

__device__ __forceinline__ unsigned short f2bf(float f) {
  unsigned int u = __builtin_bit_cast(unsigned int, f);
  u += 0x7fffu + ((u >> 16) & 1u);   // round-to-nearest-even
  return (unsigned short)(u >> 16);
}

__device__ __forceinline__ float bf2f(unsigned short u) {
  return __builtin_bit_cast(float, (unsigned int)u << 16);
}

// pack 2 fp32 -> 2 bf16 in one instr (no builtin on gfx950; RNE)
__device__ __forceinline__ unsigned int cvtpk(float lo, float hi) {
  unsigned int r;
  asm volatile("v_cvt_pk_bf16_f32 %0, %1, %2" : "=v"(r) : "v"(lo), "v"(hi));
  return r;
}

// async global -> LDS, 16B per lane.  LDS dst = wave-uniform base + lane*16.
// GLOBAL src is PER-LANE — caller must include the lane offset.
__device__ __forceinline__ void gld16(const unsigned short* g, unsigned short* l) {
  __builtin_amdgcn_global_load_lds(
      (const __attribute__((address_space(1))) unsigned int*)g,
      (__attribute__((address_space(3))) unsigned int*)l, 16, 0, 0);
}

// ---------------- prep (single dispatch): X cvt | weights cvt | rope table ----------------
__global__ void prep_all(const float* __restrict__ x,
                         const float* __restrict__ qw, const float* __restrict__ kw,
                         const float* __restrict__ vw, const float* __restrict__ ow,
                         unsigned short* __restrict__ Xb,
                         unsigned short* __restrict__ Wqb,
                         float2* __restrict__ ct2) {
  constexpr int NX = M_TOT * D_MODEL / 4;     // 2^20 float4 groups
  constexpr int NW = D_MODEL * D_MODEL;       // 2^20 float4 groups (4 weights)
  const int i = blockIdx.x * blockDim.x + threadIdx.x;
  if (i < NX) {
    const float4 v = reinterpret_cast<const float4*>(x)[i];
    ushort4 o;
    o.x = f2bf(v.x); o.y = f2bf(v.y); o.z = f2bf(v.z); o.w = f2bf(v.w);
    reinterpret_cast<ushort4*>(Xb)[i] = o;
  } else if (i < NX + NW) {
    const int k = i - NX;
    const int which = k >> 18;
    const int off = k & 262143;
    const float* src = (which == 0) ? qw : (which == 1) ? kw : (which == 2) ? vw : ow;
    const float4 v = reinterpret_cast<const float4*>(src)[off];
    ushort4 o;
    o.x = f2bf(v.x); o.y = f2bf(v.y); o.z = f2bf(v.z); o.w = f2bf(v.w);
    reinterpret_cast<ushort4*>(Wqb)[k] = o;
  } else {
    const int k = i - NX - NW;                // < SEQ*32
    const int s = k >> 5;
    const int p = k & 31;
    const float inv_freq = powf(10000.0f, -(float)p / 32.0f);
    const float ang = (float)s * inv_freq;
    const int psw = p ^ (((s >> 2) & 1) << 3);
    float2 cs; cs.x = cosf(ang); cs.y = sinf(ang);
    ct2[s * 32 + psw] = cs;
  }
}

// ---------------- GEMM v5 (round-16 proven): BK=64, counted-vmcnt, fast epilogue ----------------
template <int BM, int BN, int MODE>
__global__ __launch_bounds__(256, 2)
void gemm2(const unsigned short* __restrict__ A,
           const unsigned short* __restrict__ W,
           unsigned short* __restrict__ Qd,
           unsigned short* __restrict__ Kd,
           unsigned short* __restrict__ Vd,
           float* __restrict__ Fd,
           const float2* __restrict__ ct2) {
  constexpr int MI = BM / 32, NI = BN / 32;
  constexpr int NKT = D_MODEL / 64;            // 16 k-steps (BK=64)
  constexpr int LOADS = BM / 32 + BN / 32;     // gld16 per wave per stage
  __shared__ __align__(16) unsigned short smem[2 * (BM + BN) * 64];
  unsigned short* Asm = smem;                  // [2][BM*64]
  unsigned short* Bsm = smem + 2 * BM * 64;    // [2][BN*64]
  const int tid  = threadIdx.x;
  const int lane = tid & 63;
  const int wave = tid >> 6;
  const int wm = wave >> 1, wn = wave & 1;
  const int m0 = blockIdx.y * BM;
  const int n0 = blockIdx.x * BN;
  const int lr = lane & 15, lg = lane >> 4;

  auto stage = [&](int buf, int kt) {
    const int k0 = kt * 64;
#pragma unroll
    for (int c = 0; c < BM / 32; ++c) {
      const int ch = c * 4 + wave;
      const int row = ch * 8 + (lane >> 3);
      gld16(&A[(size_t)(m0 + row) * D_MODEL + k0 + ((lane & 7) ^ (row & 7)) * 8],
            &Asm[buf * BM * 64 + ch * 512]);
    }
#pragma unroll
    for (int c = 0; c < BN / 32; ++c) {
      const int ch = c * 4 + wave;
      const int row = ch * 8 + (lane >> 3);
      gld16(&W[(size_t)(n0 + row) * D_MODEL + k0 + ((lane & 7) ^ (row & 7)) * 8],
            &Bsm[buf * BN * 64 + ch * 512]);
    }
  };

  f32x4 acc[MI][NI] = {};

  stage(0, 0);
  stage(1, 1);
  __builtin_amdgcn_sched_barrier(0);

  for (int kt = 0; kt < NKT; ++kt) {
    const int cur = kt & 1;
    if (kt + 1 < NKT) {
      if constexpr (LOADS == 8) asm volatile("s_waitcnt vmcnt(8)" ::: "memory");
      else                      asm volatile("s_waitcnt vmcnt(6)" ::: "memory");
    } else {
      asm volatile("s_waitcnt vmcnt(0)" ::: "memory");
    }
    __builtin_amdgcn_s_barrier();
    __builtin_amdgcn_sched_barrier(0);

    bf16x8 af[MI][2], bfr[NI][2];
#pragma unroll
    for (int i = 0; i < MI; ++i)
#pragma unroll
      for (int ks = 0; ks < 2; ++ks) {
        const int R = wm * (BM / 2) + i * 16 + lr;
        const int p = (ks * 4 + lg) ^ (R & 7);
        af[i][ks] = *reinterpret_cast<const bf16x8*>(&Asm[cur * BM * 64 + R * 64 + p * 8]);
      }
#pragma unroll
    for (int j = 0; j < NI; ++j)
#pragma unroll
      for (int ks = 0; ks < 2; ++ks) {
        const int R = wn * (BN / 2) + j * 16 + lr;
        const int p = (ks * 4 + lg) ^ (R & 7);
        bfr[j][ks] = *reinterpret_cast<const bf16x8*>(&Bsm[cur * BN * 64 + R * 64 + p * 8]);
      }
    asm volatile("s_waitcnt lgkmcnt(0)" ::: "memory");
    __builtin_amdgcn_sched_barrier(0);
    __builtin_amdgcn_s_barrier();            // all waves done reading buf cur
    __builtin_amdgcn_sched_barrier(0);

    if (kt + 2 < NKT) stage(cur, kt + 2);
    __builtin_amdgcn_sched_barrier(0);

#pragma unroll
    for (int ks = 0; ks < 2; ++ks)
#pragma unroll
      for (int i = 0; i < MI; ++i)
#pragma unroll
        for (int j = 0; j < NI; ++j)
          acc[i][j] = __builtin_amdgcn_mfma_f32_16x16x32_bf16(af[i][ks], bfr[j][ks], acc[i][j], 0, 0, 0);
  }
  // loop's final read-complete s_barrier has synced all waves; smem is dead.

  if constexpr (MODE == 2) {
#pragma unroll
    for (int i = 0; i < MI; ++i)
#pragma unroll
      for (int j = 0; j < NI; ++j)
#pragma unroll
        for (int r = 0; r < 4; ++r) {
          const int gm = m0 + wm * (BM / 2) + i * 16 + lg * 4 + r;
          const int gc = n0 + wn * (BN / 2) + j * 16 + lr;
          Fd[(size_t)gm * D_MODEL + gc] = acc[i][j][r];
        }
  } else {
    const int t = n0 >> 10;                    // uniform per block
    const int b = m0 >> 11;
    const int s_base = m0 & 2047;
    if (t < 2) {
      // ---- Q/K: RoPE via LDS table ----
      unsigned short* dstQ = (t == 0) ? Qd : Kd;
      const unsigned short* gsrc = (const unsigned short*)(ct2 + (size_t)s_base * 32);
#pragma unroll
      for (int it = 0; it < 8; ++it) {
        const int ch = wave * 8 + it;
        gld16(&gsrc[ch * 512 + lane * 8], &smem[ch * 512]);
      }
      asm volatile("s_waitcnt vmcnt(0)" ::: "memory");
      __builtin_amdgcn_sched_barrier(0);
      __builtin_amdgcn_s_barrier();
      const float2* tbl = (const float2*)smem;
      const int nbase = (n0 & 1023) >> 6;
#pragma unroll
      for (int i = 0; i < MI; ++i) {
#pragma unroll
        for (int j = 0; j < NI; ++j) {
#pragma unroll
          for (int r = 0; r < 4; ++r) {
            const int sl = wm * (BM / 2) + i * 16 + lg * 4 + r;   // s_local 0..127
            const int h  = j * 16 + lr;                            // 0..63
            const int psw = (h >> 1) ^ (((sl >> 2) & 1) << 3);
            const float2 cs = tbl[sl * 32 + psw];
            float x = acc[i][j][r];
            const float part = __shfl_xor(x, 1, 64);
            x = (h & 1) ? (part * cs.y + x * cs.x) : (x * cs.x - part * cs.y);
            const int n = nbase + wn;
            dstQ[(size_t)((b * 16 + n) * SEQ + s_base + sl) * 64 + h] = f2bf(x);
          }
        }
      }
    } else {
      // ---- V: transpose via LDS, coalesced [bn][h][s] stores ----
      unsigned short* tile = smem;             // [64 cols][136]
      const int row = tid >> 2;                // 0..63
      const int ck  = tid & 3;
      for (int pass = 0; pass < 2; ++pass) {
        __builtin_amdgcn_s_barrier();
        if (wn == pass) {
#pragma unroll
          for (int i = 0; i < MI; ++i)
#pragma unroll
            for (int j = 0; j < NI; ++j)
#pragma unroll
              for (int r = 0; r < 4; ++r)
                tile[(j * 16 + lr) * 136 + wm * 64 + i * 16 + lg * 4 + r] = f2bf(acc[i][j][r]);
        }
        asm volatile("s_waitcnt lgkmcnt(0)" ::: "memory");
        __builtin_amdgcn_sched_barrier(0);
        __builtin_amdgcn_s_barrier();
        const int c = (n0 & 1023) + pass * 64 + row;
        const int n = c >> 6, h = c & 63;
        unsigned short* vrow = &Vd[(size_t)((b * 16 + n) * 64 + h) * SEQ + s_base + ck * 32];
        const unsigned short* lrow = &tile[row * 136 + ck * 32];
#pragma unroll
        for (int k = 0; k < 4; ++k)
          *reinterpret_cast<bf16x8*>(&vrow[k * 8]) = *reinterpret_cast<const bf16x8*>(&lrow[k * 8]);
      }
    }
  }
}

// ---------------- flash attention v15: split-K over heavy q-tiles ----------------
// Unnormalized softmax => partials merge LINEARLY: O = (O0+O1)/(ls0+ls1).
// y<16: split blocks, j = 15-(y>>1) in [8,16), half = y&1:
//   half 0 = tiles [0, j+1)  (provably fully unmasked), half 1 = [j+1, 2j+2).
//   Write bf16 partial O + f32 partial ls to dead-workspace scratch.
// y>=16: unsplit j = 23-y in [0,8), nt = 2j+2 <= 16, write AO directly.
// Max serial chain = 16 tiles (was 32).  Core = round-16 proven (4 waves, swapped
// QK^T, cvt_pk P in registers, counted vmcnt(4), raw barriers, swizzled LDS K/V).
__global__ __launch_bounds__(256, 2)
void attn_kernel(const unsigned short* __restrict__ Q,
                 const unsigned short* __restrict__ K,
                 const unsigned short* __restrict__ Vt,
                 unsigned short* __restrict__ AO,
                 unsigned short* __restrict__ po,   // [512][128*64] bf16 partial O
                 float* __restrict__ pl) {          // [512][128]    f32 partial ls
  __shared__ __align__(16) unsigned short Ksh[2][4096];  // [buf][64 x 64] swizzled
  __shared__ __align__(16) unsigned short Vsh[2][4096];
  const int bn   = blockIdx.x;
  const int y    = blockIdx.y;
  const bool split = (y < 16);
  const int j    = split ? (15 - (y >> 1)) : (23 - y);
  const int half = split ? (y & 1) : 0;
  const int t0   = (split && half) ? (j + 1) : 0;
  const int tend = (split && !half) ? (j + 1) : (2 * j + 2);
  const int wave = threadIdx.x >> 6;
  const int lane = threadIdx.x & 63;
  const int lr = lane & 15, lg = lane >> 4;
  const int q0 = j * 128 + wave * 32;
  const unsigned short* Qh = Q  + (size_t)bn * SEQ * 64;
  const unsigned short* Kh = K  + (size_t)bn * SEQ * 64;
  const unsigned short* Vh = Vt + (size_t)bn * 64 * SEQ;
  const int b = bn >> 4, n = bn & 15;

  const int srow8 = lane >> 3;
  const int scolb = ((lane & 7) ^ srow8) * 8;

  auto stage = [&](int buf, int k0) {
#pragma unroll
    for (int c = 0; c < 2; ++c) {
      const int ch = wave * 2 + c;
      const int row = ch * 8 + srow8;
      gld16(&Kh[(size_t)(k0 + row) * 64 + scolb], &Ksh[buf][ch * 512]);
      gld16(&Vh[(size_t)row * SEQ + k0 + scolb], &Vsh[buf][ch * 512]);
    }
  };

  constexpr float KL2E = 0.125f * 1.44269504088896f;

  bf16x8 qf[2][2];
#pragma unroll
  for (int mi = 0; mi < 2; ++mi)
#pragma unroll
    for (int ks = 0; ks < 2; ++ks)
      qf[mi][ks] = *reinterpret_cast<const bf16x8*>(
          &Qh[(size_t)(q0 + mi * 16 + lr) * 64 + ks * 32 + lg * 8]);
  asm volatile("s_waitcnt vmcnt(0)" ::: "memory");  // clean slate for counted waits
  __builtin_amdgcn_sched_barrier(0);

  f32x4 o[2][4] = {};
  float ls[2] = {0.f, 0.f};                    // row-sum for q = mi*16+lr (in-lane k)

  stage(0, t0 * 64);
  stage(1, (t0 + 1) * 64);
  __builtin_amdgcn_sched_barrier(0);

  for (int t = t0; t < tend; ++t) {
    const int cur = (t - t0) & 1;
    const int k0 = t * 64;
    if (t + 1 < tend) { asm volatile("s_waitcnt vmcnt(4)" ::: "memory"); }
    else              { asm volatile("s_waitcnt vmcnt(0)" ::: "memory"); }
    __builtin_amdgcn_s_barrier();            // all waves' stage(t) visible
    __builtin_amdgcn_sched_barrier(0);

    const unsigned short* Kc = &Ksh[cur][0];
    const unsigned short* Vc = &Vsh[cur][0];

    // ---- K frags (XOR-swizzled read) + swapped QK^T ----
    bf16x8 kf[4][2];
#pragma unroll
    for (int nj = 0; nj < 4; ++nj)
#pragma unroll
      for (int ks = 0; ks < 2; ++ks) {
        const int R = nj * 16 + lr;
        const int p = (ks * 4 + lg) ^ (R & 7);
        kf[nj][ks] = *reinterpret_cast<const bf16x8*>(&Kc[R * 64 + p * 8]);
      }
    f32x4 sf[2][4] = {};   // sf[mi][nj][r] = S[q=q0+mi*16+lr][k=k0+nj*16+lg*4+r]
    __builtin_amdgcn_s_setprio(1);
#pragma unroll
    for (int nj = 0; nj < 4; ++nj)
#pragma unroll
      for (int ks = 0; ks < 2; ++ks)
#pragma unroll
        for (int mi = 0; mi < 2; ++mi)
          sf[mi][nj] = __builtin_amdgcn_mfma_f32_16x16x32_bf16(kf[nj][ks], qf[mi][ks], sf[mi][nj], 0, 0, 0);
    __builtin_amdgcn_s_setprio(0);

    // ---- V B-frags (b64: 4 consecutive s at row h) — latency hides under exp ----
    bf16x4 vB[4][4];   // [nj][hf]: V[k0+nj*16+lg*4+{0..3}][hf*16+lr]
#pragma unroll
    for (int nj = 0; nj < 4; ++nj)
#pragma unroll
      for (int hf = 0; hf < 4; ++hf) {
        const int R = hf * 16 + lr;
        const int c = nj * 2 + (lg >> 1);
        const int p = ((c ^ (R & 7)) << 3) + (lg & 1) * 4;
        vB[nj][hf] = *reinterpret_cast<const bf16x4*>(&Vc[R * 64 + p]);
      }

    // ---- exp + pack(bf16x2) into registers (no LDS) ----
    u32x2 w[2][4];     // w[mi][nj] = P[q=lr][k=nj*16+lg*4+{0..3}] packed bf16
    if (k0 + 63 <= q0) {                       // fully unmasked (wave-uniform)
#pragma unroll
      for (int mi = 0; mi < 2; ++mi)
#pragma unroll
        for (int nj = 0; nj < 4; ++nj) {
          const float p0 = __builtin_amdgcn_exp2f(sf[mi][nj][0] * KL2E);
          const float p1 = __builtin_amdgcn_exp2f(sf[mi][nj][1] * KL2E);
          const float p2 = __builtin_amdgcn_exp2f(sf[mi][nj][2] * KL2E);
          const float p3 = __builtin_amdgcn_exp2f(sf[mi][nj][3] * KL2E);
          ls[mi] += (p0 + p1) + (p2 + p3);
          w[mi][nj][0] = cvtpk(p0, p1);
          w[mi][nj][1] = cvtpk(p2, p3);
        }
    } else {
#pragma unroll
      for (int mi = 0; mi < 2; ++mi) {
        const int qrow = q0 + mi * 16 + lr;
#pragma unroll
        for (int nj = 0; nj < 4; ++nj) {
          const int kb = k0 + nj * 16 + lg * 4;
          float p[4];
#pragma unroll
          for (int r = 0; r < 4; ++r)
            p[r] = (kb + r <= qrow) ? __builtin_amdgcn_exp2f(sf[mi][nj][r] * KL2E) : 0.0f;
          ls[mi] += (p[0] + p[1]) + (p[2] + p[3]);
          w[mi][nj][0] = cvtpk(p[0], p[1]);
          w[mi][nj][1] = cvtpk(p[2], p[3]);
        }
      }
    }

    asm volatile("s_waitcnt lgkmcnt(0)" ::: "memory");   // kf + vB reads done
    __builtin_amdgcn_sched_barrier(0);
    __builtin_amdgcn_s_barrier();            // all waves done reading buf cur
    __builtin_amdgcn_sched_barrier(0);

    if (t + 2 < tend) stage(cur, (t + 2) * 64);
    __builtin_amdgcn_sched_barrier(0);

    // ---- PV: pure-register 16x16x16 MFMA (A = packed P, B = vB) ----
    __builtin_amdgcn_s_setprio(1);
#pragma unroll
    for (int nj = 0; nj < 4; ++nj)
#pragma unroll
      for (int hf = 0; hf < 4; ++hf)
#pragma unroll
        for (int mi = 0; mi < 2; ++mi)
          o[mi][hf] = __builtin_amdgcn_mfma_f32_16x16x16bf16_1k(
              __builtin_bit_cast(bf16x4, w[mi][nj]), vB[nj][hf], o[mi][hf], 0, 0, 0);
    __builtin_amdgcn_s_setprio(0);
  }

  // ---- final reduce: lanes sharing lr hold partial sums for q=mi*16+lr ----
#pragma unroll
  for (int mi = 0; mi < 2; ++mi) {
    float s = ls[mi];
    s += __shfl_xor(s, 16, 64);
    s += __shfl_xor(s, 32, 64);
    ls[mi] = s;
  }

  if (!split) {
    // direct: normalize + store AO
#pragma unroll
    for (int mi = 0; mi < 2; ++mi)
#pragma unroll
      for (int r = 0; r < 4; ++r) {
        const float sv = __shfl(ls[mi], lg * 4 + r, 64);
        const float inv = 1.0f / sv;
        const int srow = q0 + mi * 16 + lg * 4 + r;
#pragma unroll
        for (int hf = 0; hf < 4; ++hf) {
          const int h = hf * 16 + lr;
          AO[(size_t)(b * SEQ + srow) * D_MODEL + n * 64 + h] = f2bf(o[mi][hf][r] * inv);
        }
      }
  } else {
    // partial: store unnormalized O (bf16) + ls (f32)
    const int pb = (bn * 8 + (j - 8)) * 2 + half;        // 0..511
    unsigned short* pod = po + (size_t)pb * (128 * 64);
    float* pld = pl + (size_t)pb * 128;
    if (lg == 0) {
#pragma unroll
      for (int mi = 0; mi < 2; ++mi)
        pld[wave * 32 + mi * 16 + lr] = ls[mi];
    }
#pragma unroll
    for (int mi = 0; mi < 2; ++mi)
#pragma unroll
      for (int r = 0; r < 4; ++r) {
        const int row = wave * 32 + mi * 16 + lg * 4 + r;
#pragma unroll
        for (int hf = 0; hf < 4; ++hf)
          pod[row * 64 + hf * 16 + lr] = f2bf(o[mi][hf][r]);
      }
  }
}

// ---------------- merge: AO = (O0+O1)/(ls0+ls1) for split q-tiles (j in [8,16)) ----------------
__global__ void attn_merge(const unsigned short* __restrict__ po,
                           const float* __restrict__ pl,
                           unsigned short* __restrict__ AO) {
  const int i = blockIdx.x * blockDim.x + threadIdx.x;   // < 262144 (8 h per thread)
  const int g   = i & 7;
  const int row = (i >> 3) & 127;
  const int jj  = (i >> 10) & 7;
  const int bn  = i >> 13;
  const int pb0 = (bn * 8 + jj) * 2;
  const float l = pl[pb0 * 128 + row] + pl[(pb0 + 1) * 128 + row];
  const float inv = 1.0f / l;
  const bf16x8 a = *reinterpret_cast<const bf16x8*>(&po[(size_t)pb0 * 8192 + row * 64 + g * 8]);
  const bf16x8 c = *reinterpret_cast<const bf16x8*>(&po[(size_t)(pb0 + 1) * 8192 + row * 64 + g * 8]);
  bf16x8 out;
#pragma unroll
  for (int e = 0; e < 8; ++e)
    out[e] = (short)f2bf((bf2f((unsigned short)a[e]) + bf2f((unsigned short)c[e])) * inv);
  const int s = (jj + 8) * 128 + row;
  const int b = bn >> 4, n = bn & 15;
  *reinterpret_cast<bf16x8*>(&AO[(size_t)(b * SEQ + s) * D_MODEL + n * 64 + g * 8]) = out;
}

// ---------------- launch ----------------
extern "C" void kernel_launch(void* const* d_in, const int* in_sizes, int n_in,
                              void* d_out, int out_size, void* d_ws, size_t ws_size,
                              hipStream_t stream) {
  const float* qw = (const float*)d_in[0];
  const float* kw = (const float*)d_in[1];
  const float* vw = (const float*)d_in[2];
  const float* ow = (const float*)d_in[3];
  const float* x  = (const float*)d_in[4];

  char* ws = (char*)d_ws;
  const size_t XB = (size_t)M_TOT * D_MODEL * 2;      // 8 MB
  const size_t WB = (size_t)D_MODEL * D_MODEL * 2;    // 2 MB
  unsigned short* Xb  = (unsigned short*)ws;  ws += XB;
  unsigned short* Wqb = (unsigned short*)ws;  ws += WB;  // Wq|Wk|Wv|Wo contiguous
  unsigned short* Wkb = (unsigned short*)ws;  ws += WB;
  unsigned short* Wvb = (unsigned short*)ws;  ws += WB;
  unsigned short* Wob = (unsigned short*)ws;  ws += WB;
  unsigned short* Qr  = (unsigned short*)ws;  ws += XB;
  unsigned short* Kr  = (unsigned short*)ws;  ws += XB;
  unsigned short* Vt  = (unsigned short*)ws;  ws += XB;
  unsigned short* AO  = (unsigned short*)ws;  ws += XB;
  float2* ct2 = (float2*)ws;  ws += (size_t)SEQ * 32 * 8;   // interleaved rope table
  (void)Wkb; (void)Wvb;

  // split-K scratch overlays buffers that are DEAD after the QKV GEMM:
  unsigned short* po = Xb;              // 512 * 8192 bf16 = 8 MB  (Xb dead post-QKV)
  float*          pl = (float*)Wqb;     // 512 * 128 f32 = 256 KB  (Wqb dead post-QKV)

  // fused prep: X cvt (2^20) + weights cvt (2^20) + rope (65536) in one dispatch
  constexpr int PREP_ITEMS = M_TOT * D_MODEL / 4 + D_MODEL * D_MODEL + SEQ * 32;
  prep_all<<<(PREP_ITEMS + 255) / 256, 256, 0, stream>>>(x, qw, kw, vw, ow, Xb, Wqb, ct2);

  // merged QKV projection: N = 3072
  gemm2<128, 128, 0><<<dim3(3072 / 128, M_TOT / 128), 256, 0, stream>>>(
      Xb, Wqb, Qr, Kr, Vt, nullptr, ct2);

  // split-K attention: y<16 = split halves of j in [8,16) (heavy-first), y>=16 = j in [0,8)
  attn_kernel<<<dim3(BATCH * 16, 24), 256, 0, stream>>>(Qr, Kr, Vt, AO, po, pl);

  // merge split partials into AO rows s >= 1024
  attn_merge<<<262144 / 256, 256, 0, stream>>>(po, pl, AO);

  // final projection: N = 1024, 128x64 tile -> 512 blocks
  gemm2<128, 64, 2><<<dim3(D_MODEL / 64, M_TOT / 128), 256, 0, stream>>>(
      AO, Wob, nullptr, nullptr, nullptr, (float*)d_out, nullptr);
}